// Round 1
// baseline (388.871 us; speedup 1.0000x reference)
//
#include <hip/hip_runtime.h>
#include <hip/hip_bf16.h>

// GCN: h=tanh(x@encW+encb); 3x { hw=h@Wi; agg=segment_sum(hw[src]*ew, dst); h=tanh(agg+bi) }; out=h@decW+decb
// Strategy round 0: fp32 everywhere (correctness-first).
//  - row-tiled vector GEMM (K=128 fixed), A-tile in LDS, W streamed from L1/L2
//  - CSR-by-dst built per call (histogram -> single-block scan -> atomic scatter)
//  - pull aggregation: 1 wave per dst node, 2 f32/lane register accumulators, no atomics

#define NNODES 10000
#define NEDGES 640000
#define HDIM   128
#define CDIM   64
#define NLAYER 3

// ---------------- GEMM: out[M,NCOLS] = A[M,128] @ W[128,NCOLS] (+bias)(+tanh) ----------------
template<int NCOLS, bool BIAS, bool TANH>
__global__ __launch_bounds__(256) void gemm_rowtile(
    const float* __restrict__ A,     // [M,128] row-major
    const float* __restrict__ W,     // [128,NCOLS] row-major
    const float* __restrict__ bias,  // [NCOLS] or nullptr
    float* __restrict__ out,         // [M,NCOLS]
    int M)
{
    constexpr int K  = 128;
    constexpr int TR = 16;            // rows per block (M=10000 divisible by 16)
    constexpr int CG = NCOLS / 4;     // float4 col groups
    constexpr int RT = 256 / CG;      // distinct row-threads
    constexpr int RPT = TR / RT;      // rows per thread

    __shared__ float Alds[TR][K + 4];

    const int tid  = threadIdx.x;
    const int base = blockIdx.x * TR;

    // stage A tile (16x128 f32 = 8KB) via float4
    for (int idx = tid; idx < TR * (K / 4); idx += 256) {
        int r  = idx / (K / 4);
        int kk = idx % (K / 4);
        float4 v = *(const float4*)(A + (size_t)(base + r) * K + kk * 4);
        *(float4*)(&Alds[r][kk * 4]) = v;
    }
    __syncthreads();

    const int cg = tid % CG;
    const int rt = tid / CG;
    const int c0 = cg * 4;

    float4 acc[RPT];
    #pragma unroll
    for (int j = 0; j < RPT; ++j) acc[j] = make_float4(0.f, 0.f, 0.f, 0.f);

    #pragma unroll 4
    for (int k = 0; k < K; ++k) {
        float4 b = *(const float4*)(W + k * NCOLS + c0);
        #pragma unroll
        for (int j = 0; j < RPT; ++j) {
            float a = Alds[rt + j * RT][k];
            acc[j].x += a * b.x;
            acc[j].y += a * b.y;
            acc[j].z += a * b.z;
            acc[j].w += a * b.w;
        }
    }

    float4 bv = make_float4(0.f, 0.f, 0.f, 0.f);
    if (BIAS) bv = *(const float4*)(bias + c0);

    #pragma unroll
    for (int j = 0; j < RPT; ++j) {
        int r = base + rt + j * RT;
        float4 o;
        o.x = acc[j].x + bv.x;
        o.y = acc[j].y + bv.y;
        o.z = acc[j].z + bv.z;
        o.w = acc[j].w + bv.w;
        if (TANH) {
            o.x = tanhf(o.x); o.y = tanhf(o.y); o.z = tanhf(o.z); o.w = tanhf(o.w);
        }
        *(float4*)(out + (size_t)r * NCOLS + c0) = o;
    }
}

// ---------------- CSR build ----------------
__global__ __launch_bounds__(256) void zero_i32(int* __restrict__ p, int n) {
    int i = blockIdx.x * blockDim.x + threadIdx.x;
    if (i < n) p[i] = 0;
}

__global__ __launch_bounds__(256) void hist_kernel(const int* __restrict__ dst, int E, int* __restrict__ cnt) {
    int e = blockIdx.x * blockDim.x + threadIdx.x;
    if (e < E) atomicAdd(cnt + dst[e], 1);
}

__global__ __launch_bounds__(1024) void scan_kernel(const int* __restrict__ cnt,
                                                    int* __restrict__ rs,
                                                    int* __restrict__ cur,
                                                    int N)
{
    __shared__ int part[1024];
    const int t = threadIdx.x;
    const int per = (N + 1023) / 1024;   // 10
    const int begin = t * per;
    int s = 0;
    for (int j = 0; j < per; ++j) {
        int i = begin + j;
        if (i < N) s += cnt[i];
    }
    part[t] = s;
    __syncthreads();
    // Hillis-Steele inclusive scan
    for (int off = 1; off < 1024; off <<= 1) {
        int v = (t >= off) ? part[t - off] : 0;
        __syncthreads();
        part[t] += v;
        __syncthreads();
    }
    int excl = part[t] - s;   // exclusive prefix for this thread's chunk
    for (int j = 0; j < per; ++j) {
        int i = begin + j;
        if (i < N) {
            rs[i]  = excl;
            cur[i] = excl;
            excl += cnt[i];
        }
    }
    if (t == 1023) rs[N] = part[1023];
}

__global__ __launch_bounds__(256) void scatter_kernel(const int* __restrict__ src,
                                                      const int* __restrict__ dst,
                                                      const float* __restrict__ ew,
                                                      int E,
                                                      int* __restrict__ cur,
                                                      int* __restrict__ csr_src,
                                                      float* __restrict__ csr_w)
{
    int e = blockIdx.x * blockDim.x + threadIdx.x;
    if (e < E) {
        int d = dst[e];
        int p = atomicAdd(cur + d, 1);
        csr_src[p] = src[e];
        csr_w[p]   = ew[e];
    }
}

// ---------------- pull aggregation: 1 wave per dst node ----------------
__global__ __launch_bounds__(256) void aggregate_kernel(
    const float* __restrict__ hw,      // [N,128]
    const int* __restrict__ rs,        // [N+1]
    const int* __restrict__ csr_src,   // [E]
    const float* __restrict__ csr_w,   // [E]
    const float* __restrict__ bias,    // [128]
    float* __restrict__ hout,          // [N,128]
    int N)
{
    const int wid  = (blockIdx.x * blockDim.x + threadIdx.x) >> 6;  // wave id = node
    const int lane = threadIdx.x & 63;
    if (wid >= N) return;

    const int e0 = rs[wid];
    const int e1 = rs[wid + 1];

    float acc0 = 0.f, acc1 = 0.f;
    for (int e = e0; e < e1; ++e) {
        int s   = csr_src[e];     // wave-uniform broadcast load
        float w = csr_w[e];
        const float* p = hw + (size_t)s * HDIM;
        acc0 += w * p[lane];
        acc1 += w * p[lane + 64];
    }
    hout[(size_t)wid * HDIM + lane]      = tanhf(acc0 + bias[lane]);
    hout[(size_t)wid * HDIM + 64 + lane] = tanhf(acc1 + bias[lane + 64]);
}

// ---------------- launch ----------------
extern "C" void kernel_launch(void* const* d_in, const int* in_sizes, int n_in,
                              void* d_out, int out_size, void* d_ws, size_t ws_size,
                              hipStream_t stream)
{
    const float* x      = (const float*)d_in[0];
    const int*   ei     = (const int*)  d_in[1];   // [2,E] (src row then dst row)
    const float* ew     = (const float*)d_in[2];
    const float* enc_W  = (const float*)d_in[3];
    const float* enc_b  = (const float*)d_in[4];
    const float* conv_W = (const float*)d_in[5];   // [L,H,H]
    const float* conv_b = (const float*)d_in[6];   // [L,H]
    const float* dec_W  = (const float*)d_in[7];   // [H,C]
    const float* dec_b  = (const float*)d_in[8];   // [C]
    float* out = (float*)d_out;

    const int N = NNODES, E = NEDGES, H = HDIM;

    // workspace layout (all 16B-aligned by construction)
    float* h   = (float*)d_ws;                 // [N,H]
    float* hw  = h + (size_t)N * H;            // [N,H]
    int*   cnt = (int*)(hw + (size_t)N * H);   // [N]
    int*   rs  = cnt + N;                      // [N+1]
    int*   cur = rs + (N + 1);                 // [N]
    int*   csr_src = cur + N;                  // [E]
    float* csr_w   = (float*)(csr_src + E);    // [E]

    const int*   src = ei;
    const int*   dst = ei + E;

    // encoder: h = tanh(x @ enc_W + enc_b)
    gemm_rowtile<128, true, true><<<N / 16, 256, 0, stream>>>(x, enc_W, enc_b, h, N);

    // CSR build (independent of h; stream-serialized anyway)
    zero_i32<<<(N + 255) / 256, 256, 0, stream>>>(cnt, N);
    hist_kernel<<<(E + 255) / 256, 256, 0, stream>>>(dst, E, cnt);
    scan_kernel<<<1, 1024, 0, stream>>>(cnt, rs, cur, N);
    scatter_kernel<<<(E + 255) / 256, 256, 0, stream>>>(src, dst, ew, E, cur, csr_src, csr_w);

    // GCN layers
    for (int i = 0; i < NLAYER; ++i) {
        gemm_rowtile<128, false, false><<<N / 16, 256, 0, stream>>>(h, conv_W + (size_t)i * H * H, nullptr, hw, N);
        aggregate_kernel<<<(N + 3) / 4, 256, 0, stream>>>(hw, rs, csr_src, csr_w, conv_b + (size_t)i * H, h, N);
    }

    // decoder: out = h @ dec_W + dec_b
    gemm_rowtile<64, true, false><<<N / 16, 256, 0, stream>>>(h, dec_W, dec_b, out, N);
}

// Round 2
// 292.786 us; speedup vs baseline: 1.3282x; 1.3282x over previous
//
#include <hip/hip_runtime.h>
#include <hip/hip_bf16.h>

// GCN round 1: fp32, latency-oriented fixes.
//  - aggregate: 1 wave/node, edge-loop unrolled x4 (8 independent gathers in
//    flight), float2 row loads (1 dwordx2/lane instead of 2 dword)
//  - GEMM: TR=32 rows/block, RPT=4 -> 16 FMA per W-load, unroll 4

#define NNODES 10000
#define NEDGES 640000
#define HDIM   128
#define CDIM   64
#define NLAYER 3

// ---------------- GEMM: out[M,NCOLS] = A[M,128] @ W[128,NCOLS] (+bias)(+tanh) ----------------
template<int NCOLS, bool BIAS, bool TANH>
__global__ __launch_bounds__(256) void gemm_rowtile(
    const float* __restrict__ A,     // [M,128] row-major
    const float* __restrict__ W,     // [128,NCOLS] row-major
    const float* __restrict__ bias,  // [NCOLS] or nullptr
    float* __restrict__ out,         // [M,NCOLS]
    int M)
{
    constexpr int K   = 128;
    constexpr int TR  = 32;           // rows per block
    constexpr int CG  = NCOLS / 4;    // float4 col groups (32 or 16)
    constexpr int RT  = 256 / CG;     // distinct row-threads (8 or 16)
    constexpr int RPT = TR / RT;      // rows per thread (4 or 2)

    __shared__ float Alds[TR][K + 4];

    const int tid  = threadIdx.x;
    const int base = blockIdx.x * TR;

    // stage A tile (32x128 f32 = 16KB) via float4, clamp OOB rows
    for (int idx = tid; idx < TR * (K / 4); idx += 256) {
        int r  = idx / (K / 4);
        int kk = idx % (K / 4);
        int row = base + r; if (row >= M) row = M - 1;
        float4 v = *(const float4*)(A + (size_t)row * K + kk * 4);
        *(float4*)(&Alds[r][kk * 4]) = v;
    }
    __syncthreads();

    const int cg = tid % CG;
    const int rt = tid / CG;
    const int c0 = cg * 4;

    float4 acc[RPT];
    #pragma unroll
    for (int j = 0; j < RPT; ++j) acc[j] = make_float4(0.f, 0.f, 0.f, 0.f);

    #pragma unroll 4
    for (int k = 0; k < K; ++k) {
        float4 b = *(const float4*)(W + k * NCOLS + c0);
        #pragma unroll
        for (int j = 0; j < RPT; ++j) {
            float a = Alds[rt + j * RT][k];
            acc[j].x += a * b.x;
            acc[j].y += a * b.y;
            acc[j].z += a * b.z;
            acc[j].w += a * b.w;
        }
    }

    float4 bv = make_float4(0.f, 0.f, 0.f, 0.f);
    if (BIAS) bv = *(const float4*)(bias + c0);

    #pragma unroll
    for (int j = 0; j < RPT; ++j) {
        int r = base + rt + j * RT;
        if (r < M) {
            float4 o;
            o.x = acc[j].x + bv.x;
            o.y = acc[j].y + bv.y;
            o.z = acc[j].z + bv.z;
            o.w = acc[j].w + bv.w;
            if (TANH) {
                o.x = tanhf(o.x); o.y = tanhf(o.y); o.z = tanhf(o.z); o.w = tanhf(o.w);
            }
            *(float4*)(out + (size_t)r * NCOLS + c0) = o;
        }
    }
}

// ---------------- CSR build ----------------
__global__ __launch_bounds__(256) void zero_i32(int* __restrict__ p, int n) {
    int i = blockIdx.x * blockDim.x + threadIdx.x;
    if (i < n) p[i] = 0;
}

__global__ __launch_bounds__(256) void hist_kernel(const int* __restrict__ dst, int E, int* __restrict__ cnt) {
    int e = blockIdx.x * blockDim.x + threadIdx.x;
    if (e < E) atomicAdd(cnt + dst[e], 1);
}

__global__ __launch_bounds__(1024) void scan_kernel(const int* __restrict__ cnt,
                                                    int* __restrict__ rs,
                                                    int* __restrict__ cur,
                                                    int N)
{
    __shared__ int part[1024];
    const int t = threadIdx.x;
    const int per = (N + 1023) / 1024;   // 10
    const int begin = t * per;
    int s = 0;
    for (int j = 0; j < per; ++j) {
        int i = begin + j;
        if (i < N) s += cnt[i];
    }
    part[t] = s;
    __syncthreads();
    for (int off = 1; off < 1024; off <<= 1) {
        int v = (t >= off) ? part[t - off] : 0;
        __syncthreads();
        part[t] += v;
        __syncthreads();
    }
    int excl = part[t] - s;
    for (int j = 0; j < per; ++j) {
        int i = begin + j;
        if (i < N) {
            rs[i]  = excl;
            cur[i] = excl;
            excl += cnt[i];
        }
    }
    if (t == 1023) rs[N] = part[1023];
}

__global__ __launch_bounds__(256) void scatter_kernel(const int* __restrict__ src,
                                                      const int* __restrict__ dst,
                                                      const float* __restrict__ ew,
                                                      int E,
                                                      int* __restrict__ cur,
                                                      int* __restrict__ csr_src,
                                                      float* __restrict__ csr_w)
{
    int e = blockIdx.x * blockDim.x + threadIdx.x;
    if (e < E) {
        int d = dst[e];
        int p = atomicAdd(cur + d, 1);
        csr_src[p] = src[e];
        csr_w[p]   = ew[e];
    }
}

// ---------------- pull aggregation: 1 wave per dst node, unroll x4, float2 rows ----------------
__global__ __launch_bounds__(256) void aggregate_kernel(
    const float* __restrict__ hw,      // [N,128]
    const int* __restrict__ rs,        // [N+1]
    const int* __restrict__ csr_src,   // [E]
    const float* __restrict__ csr_w,   // [E]
    const float* __restrict__ bias,    // [128]
    float* __restrict__ hout,          // [N,128]
    int N)
{
    const int wid  = (blockIdx.x * blockDim.x + threadIdx.x) >> 6;  // wave id = node
    const int lane = threadIdx.x & 63;
    if (wid >= N) return;

    const int e0 = rs[wid];
    const int e1 = rs[wid + 1];

    float ax = 0.f, ay = 0.f;
    int e = e0;
    for (; e + 4 <= e1; e += 4) {
        int   s0 = csr_src[e + 0], s1 = csr_src[e + 1], s2 = csr_src[e + 2], s3 = csr_src[e + 3];
        float w0 = csr_w[e + 0],  w1 = csr_w[e + 1],  w2 = csr_w[e + 2],  w3 = csr_w[e + 3];
        float2 v0 = ((const float2*)(hw + ((size_t)s0 << 7)))[lane];
        float2 v1 = ((const float2*)(hw + ((size_t)s1 << 7)))[lane];
        float2 v2 = ((const float2*)(hw + ((size_t)s2 << 7)))[lane];
        float2 v3 = ((const float2*)(hw + ((size_t)s3 << 7)))[lane];
        ax += w0 * v0.x; ay += w0 * v0.y;
        ax += w1 * v1.x; ay += w1 * v1.y;
        ax += w2 * v2.x; ay += w2 * v2.y;
        ax += w3 * v3.x; ay += w3 * v3.y;
    }
    for (; e < e1; ++e) {
        int s   = csr_src[e];
        float w = csr_w[e];
        float2 v = ((const float2*)(hw + ((size_t)s << 7)))[lane];
        ax += w * v.x; ay += w * v.y;
    }

    float2 b = ((const float2*)bias)[lane];
    float2 o;
    o.x = tanhf(ax + b.x);
    o.y = tanhf(ay + b.y);
    ((float2*)(hout + ((size_t)wid << 7)))[lane] = o;
}

// ---------------- launch ----------------
extern "C" void kernel_launch(void* const* d_in, const int* in_sizes, int n_in,
                              void* d_out, int out_size, void* d_ws, size_t ws_size,
                              hipStream_t stream)
{
    const float* x      = (const float*)d_in[0];
    const int*   ei     = (const int*)  d_in[1];   // [2,E]
    const float* ew     = (const float*)d_in[2];
    const float* enc_W  = (const float*)d_in[3];
    const float* enc_b  = (const float*)d_in[4];
    const float* conv_W = (const float*)d_in[5];   // [L,H,H]
    const float* conv_b = (const float*)d_in[6];   // [L,H]
    const float* dec_W  = (const float*)d_in[7];   // [H,C]
    const float* dec_b  = (const float*)d_in[8];   // [C]
    float* out = (float*)d_out;

    const int N = NNODES, E = NEDGES, H = HDIM;

    float* h   = (float*)d_ws;                 // [N,H]
    float* hw  = h + (size_t)N * H;            // [N,H]
    int*   cnt = (int*)(hw + (size_t)N * H);   // [N]
    int*   rs  = cnt + N;                      // [N+1]
    int*   cur = rs + (N + 1);                 // [N]
    int*   csr_src = cur + N;                  // [E]
    float* csr_w   = (float*)(csr_src + E);    // [E]

    const int* src = ei;
    const int* dst = ei + E;

    gemm_rowtile<128, true, true><<<(N + 31) / 32, 256, 0, stream>>>(x, enc_W, enc_b, h, N);

    zero_i32<<<(N + 255) / 256, 256, 0, stream>>>(cnt, N);
    hist_kernel<<<(E + 255) / 256, 256, 0, stream>>>(dst, E, cnt);
    scan_kernel<<<1, 1024, 0, stream>>>(cnt, rs, cur, N);
    scatter_kernel<<<(E + 255) / 256, 256, 0, stream>>>(src, dst, ew, E, cur, csr_src, csr_w);

    for (int i = 0; i < NLAYER; ++i) {
        gemm_rowtile<128, false, false><<<(N + 31) / 32, 256, 0, stream>>>(h, conv_W + (size_t)i * H * H, nullptr, hw, N);
        aggregate_kernel<<<(N + 3) / 4, 256, 0, stream>>>(hw, rs, csr_src, csr_w, conv_b + (size_t)i * H, h, N);
    }

    gemm_rowtile<64, true, false><<<(N + 31) / 32, 256, 0, stream>>>(h, dec_W, dec_b, out, N);
}

// Round 3
// 277.129 us; speedup vs baseline: 1.4032x; 1.0565x over previous
//
#include <hip/hip_runtime.h>
#include <hip/hip_bf16.h>

// GCN round 3: fp32. Atomic-free CSR build (block counting sort), packed int2
// CSR payload, float4-k GEMM.

#define NNODES 10000
#define NEDGES 640000
#define HDIM   128
#define CDIM   64
#define NLAYER 3
#define NB     40            // CSR build blocks
#define CHUNK  (NEDGES / NB) // 16000 edges per block

// ---------------- GEMM: out[M,NCOLS] = A[M,128] @ W[128,NCOLS] (+bias)(+tanh) ----------------
template<int NCOLS, bool BIAS, bool TANH>
__global__ __launch_bounds__(256) void gemm_rowtile(
    const float* __restrict__ A,     // [M,128]
    const float* __restrict__ W,     // [128,NCOLS]
    const float* __restrict__ bias,  // [NCOLS]
    float* __restrict__ out,         // [M,NCOLS]
    int M)
{
    constexpr int K   = 128;
    constexpr int TR  = 16;           // rows per block (10000 % 16 == 0)
    constexpr int CG  = NCOLS / 4;    // float4 col groups (32 or 16)
    constexpr int RT  = 256 / CG;     // row-threads (8 or 16)
    constexpr int RPT = TR / RT;      // rows per thread (2 or 1)

    __shared__ float Alds[TR][K + 4];

    const int tid  = threadIdx.x;
    const int base = blockIdx.x * TR;

    // stage A tile (16x128 f32 = 8KB)
    for (int idx = tid; idx < TR * (K / 4); idx += 256) {
        int r  = idx / (K / 4);
        int kk = idx % (K / 4);
        float4 v = *(const float4*)(A + (size_t)(base + r) * K + kk * 4);
        *(float4*)(&Alds[r][kk * 4]) = v;
    }
    __syncthreads();

    const int cg = tid % CG;
    const int rt = tid / CG;
    const int c0 = cg * 4;
    const float* wp = W + c0;

    float4 acc[RPT];
    #pragma unroll
    for (int j = 0; j < RPT; ++j) acc[j] = make_float4(0.f, 0.f, 0.f, 0.f);

    #pragma unroll 4
    for (int k4 = 0; k4 < K; k4 += 4) {
        float4 b0 = *(const float4*)(wp + (k4 + 0) * NCOLS);
        float4 b1 = *(const float4*)(wp + (k4 + 1) * NCOLS);
        float4 b2 = *(const float4*)(wp + (k4 + 2) * NCOLS);
        float4 b3 = *(const float4*)(wp + (k4 + 3) * NCOLS);
        #pragma unroll
        for (int j = 0; j < RPT; ++j) {
            float4 a = *(const float4*)(&Alds[rt + j * RT][k4]);
            acc[j].x += a.x * b0.x + a.y * b1.x + a.z * b2.x + a.w * b3.x;
            acc[j].y += a.x * b0.y + a.y * b1.y + a.z * b2.y + a.w * b3.y;
            acc[j].z += a.x * b0.z + a.y * b1.z + a.z * b2.z + a.w * b3.z;
            acc[j].w += a.x * b0.w + a.y * b1.w + a.z * b2.w + a.w * b3.w;
        }
    }

    float4 bv = make_float4(0.f, 0.f, 0.f, 0.f);
    if (BIAS) bv = *(const float4*)(bias + c0);

    #pragma unroll
    for (int j = 0; j < RPT; ++j) {
        int r = base + rt + j * RT;
        float4 o;
        o.x = acc[j].x + bv.x;
        o.y = acc[j].y + bv.y;
        o.z = acc[j].z + bv.z;
        o.w = acc[j].w + bv.w;
        if (TANH) {
            o.x = tanhf(o.x); o.y = tanhf(o.y); o.z = tanhf(o.z); o.w = tanhf(o.w);
        }
        *(float4*)(out + (size_t)r * NCOLS + c0) = o;
    }
}

// ---------------- CSR build: block counting sort, no global atomics ----------------
// passA: per-block LDS histogram -> counts[b][i] (coalesced)
__global__ __launch_bounds__(1024) void passA_hist(const int* __restrict__ dst,
                                                   int* __restrict__ counts)
{
    __shared__ int hist[NNODES];
    const int b = blockIdx.x, t = threadIdx.x;
    for (int i = t; i < NNODES; i += 1024) hist[i] = 0;
    __syncthreads();
    const int e0 = b * CHUNK, e1 = e0 + CHUNK;
    for (int e = e0 + t; e < e1; e += 1024) atomicAdd(&hist[dst[e]], 1);
    __syncthreads();
    for (int i = t; i < NNODES; i += 1024) counts[b * NNODES + i] = hist[i];
}

// colsum: total[i] = sum_b counts[b][i]
__global__ __launch_bounds__(256) void colsum_kernel(const int* __restrict__ counts,
                                                     int* __restrict__ total)
{
    int i = blockIdx.x * blockDim.x + threadIdx.x;
    if (i >= NNODES) return;
    int s = 0;
    #pragma unroll
    for (int b = 0; b < NB; ++b) s += counts[b * NNODES + i];
    total[i] = s;
}

// scan: rs = exclusive_scan(total), rs[N] = E
__global__ __launch_bounds__(1024) void scan_kernel(const int* __restrict__ total,
                                                    int* __restrict__ rs)
{
    __shared__ int part[1024];
    const int t = threadIdx.x;
    const int per = (NNODES + 1023) / 1024;   // 10
    const int begin = t * per;
    int s = 0;
    for (int j = 0; j < per; ++j) {
        int i = begin + j;
        if (i < NNODES) s += total[i];
    }
    part[t] = s;
    __syncthreads();
    for (int off = 1; off < 1024; off <<= 1) {
        int v = (t >= off) ? part[t - off] : 0;
        __syncthreads();
        part[t] += v;
        __syncthreads();
    }
    int excl = part[t] - s;
    for (int j = 0; j < per; ++j) {
        int i = begin + j;
        if (i < NNODES) {
            rs[i] = excl;
            excl += total[i];
        }
    }
    if (t == 1023) rs[NNODES] = part[1023];
}

// mkbase: counts[b][i] -> base[b][i] = rs[i] + sum_{b'<b} counts[b'][i]  (in place)
__global__ __launch_bounds__(256) void mkbase_kernel(int* __restrict__ counts,
                                                     const int* __restrict__ rs)
{
    int i = blockIdx.x * blockDim.x + threadIdx.x;
    if (i >= NNODES) return;
    int run = rs[i];
    #pragma unroll
    for (int b = 0; b < NB; ++b) {
        int c = counts[b * NNODES + i];
        counts[b * NNODES + i] = run;
        run += c;
    }
}

// passB: LDS cursor per node; write packed (src, w) with no global atomics
__global__ __launch_bounds__(1024) void passB_scatter(const int* __restrict__ src,
                                                      const int* __restrict__ dst,
                                                      const float* __restrict__ ew,
                                                      const int* __restrict__ base,
                                                      int2* __restrict__ csr)
{
    __shared__ int cur[NNODES];
    const int b = blockIdx.x, t = threadIdx.x;
    for (int i = t; i < NNODES; i += 1024) cur[i] = base[b * NNODES + i];
    __syncthreads();
    const int e0 = b * CHUNK, e1 = e0 + CHUNK;
    for (int e = e0 + t; e < e1; e += 1024) {
        int d = dst[e];
        int p = atomicAdd(&cur[d], 1);
        int2 pk;
        pk.x = src[e];
        pk.y = __float_as_int(ew[e]);
        csr[p] = pk;
    }
}

// ---------------- pull aggregation: 1 wave per dst node, unroll x4 ----------------
__global__ __launch_bounds__(256) void aggregate_kernel(
    const float* __restrict__ hw,      // [N,128]
    const int* __restrict__ rs,        // [N+1]
    const int2* __restrict__ csr,      // [E] packed (src, w)
    const float* __restrict__ bias,    // [128]
    float* __restrict__ hout,          // [N,128]
    int N)
{
    const int wid  = (blockIdx.x * blockDim.x + threadIdx.x) >> 6;
    const int lane = threadIdx.x & 63;
    if (wid >= N) return;

    const int e0 = rs[wid];
    const int e1 = rs[wid + 1];

    float ax = 0.f, ay = 0.f;
    int e = e0;
    for (; e + 4 <= e1; e += 4) {
        int2 p0 = csr[e + 0], p1 = csr[e + 1], p2 = csr[e + 2], p3 = csr[e + 3];
        float2 v0 = ((const float2*)(hw + ((size_t)p0.x << 7)))[lane];
        float2 v1 = ((const float2*)(hw + ((size_t)p1.x << 7)))[lane];
        float2 v2 = ((const float2*)(hw + ((size_t)p2.x << 7)))[lane];
        float2 v3 = ((const float2*)(hw + ((size_t)p3.x << 7)))[lane];
        float w0 = __int_as_float(p0.y), w1 = __int_as_float(p1.y);
        float w2 = __int_as_float(p2.y), w3 = __int_as_float(p3.y);
        ax += w0 * v0.x; ay += w0 * v0.y;
        ax += w1 * v1.x; ay += w1 * v1.y;
        ax += w2 * v2.x; ay += w2 * v2.y;
        ax += w3 * v3.x; ay += w3 * v3.y;
    }
    for (; e < e1; ++e) {
        int2 p = csr[e];
        float w = __int_as_float(p.y);
        float2 v = ((const float2*)(hw + ((size_t)p.x << 7)))[lane];
        ax += w * v.x; ay += w * v.y;
    }

    float2 bv = ((const float2*)bias)[lane];
    float2 o;
    o.x = tanhf(ax + bv.x);
    o.y = tanhf(ay + bv.y);
    ((float2*)(hout + ((size_t)wid << 7)))[lane] = o;
}

// ---------------- launch ----------------
extern "C" void kernel_launch(void* const* d_in, const int* in_sizes, int n_in,
                              void* d_out, int out_size, void* d_ws, size_t ws_size,
                              hipStream_t stream)
{
    const float* x      = (const float*)d_in[0];
    const int*   ei     = (const int*)  d_in[1];   // [2,E]
    const float* ew     = (const float*)d_in[2];
    const float* enc_W  = (const float*)d_in[3];
    const float* enc_b  = (const float*)d_in[4];
    const float* conv_W = (const float*)d_in[5];   // [L,H,H]
    const float* conv_b = (const float*)d_in[6];   // [L,H]
    const float* dec_W  = (const float*)d_in[7];   // [H,C]
    const float* dec_b  = (const float*)d_in[8];   // [C]
    float* out = (float*)d_out;

    const int N = NNODES, E = NEDGES, H = HDIM;

    // big scratch in d_ws
    float* h   = (float*)d_ws;                      // [N,H]   5.12MB
    float* hw  = h + (size_t)N * H;                 // [N,H]   5.12MB
    int2*  csr = (int2*)(hw + (size_t)N * H);       // [E]     5.12MB
    // small scratch in d_out (2.56MB; decoder fully rewrites it at the end)
    int* counts = (int*)d_out;                      // [NB][N] 1.6MB
    int* total  = counts + NB * N;                  // [N]
    int* rs     = total + N;                        // [N+1]

    const int* src = ei;
    const int* dst = ei + E;

    gemm_rowtile<128, true, true><<<N / 16, 256, 0, stream>>>(x, enc_W, enc_b, h, N);

    passA_hist   <<<NB, 1024, 0, stream>>>(dst, counts);
    colsum_kernel<<<(N + 255) / 256, 256, 0, stream>>>(counts, total);
    scan_kernel  <<<1, 1024, 0, stream>>>(total, rs);
    mkbase_kernel<<<(N + 255) / 256, 256, 0, stream>>>(counts, rs);
    passB_scatter<<<NB, 1024, 0, stream>>>(src, dst, ew, counts, csr);

    for (int i = 0; i < NLAYER; ++i) {
        gemm_rowtile<128, false, false><<<N / 16, 256, 0, stream>>>(h, conv_W + (size_t)i * H * H, nullptr, hw, N);
        aggregate_kernel<<<(N + 3) / 4, 256, 0, stream>>>(hw, rs, csr, conv_b + (size_t)i * H, h, N);
    }

    gemm_rowtile<64, true, false><<<N / 16, 256, 0, stream>>>(h, dec_W, dec_b, out, N);
}

// Round 4
// 222.558 us; speedup vs baseline: 1.7473x; 1.2452x over previous
//
#include <hip/hip_runtime.h>
#include <hip/hip_bf16.h>
#include <hip/hip_fp16.h>

// GCN round 4: fp32 accumulate everywhere; hw table stored fp16 so the 2.56MB
// gather table is L2-resident per XCD (was 5.12MB fp32 > 4MB L2). CSR build
// with NB=200 blocks for occupancy.

#define NNODES 10000
#define NEDGES 640000
#define HDIM   128
#define CDIM   64
#define NLAYER 3
#define NB     200           // CSR build blocks
#define CHUNK  (NEDGES / NB) // 3200 edges per block

// ---------------- GEMM: out[M,NCOLS] = A[M,128] @ W[128,NCOLS] (+bias)(+tanh) ----------------
// OUTHALF: store output as fp16 (row-major [M,NCOLS] halves)
template<int NCOLS, bool BIAS, bool TANH, bool OUTHALF>
__global__ __launch_bounds__(256) void gemm_rowtile(
    const float* __restrict__ A,     // [M,128]
    const float* __restrict__ W,     // [128,NCOLS]
    const float* __restrict__ bias,  // [NCOLS]
    void* __restrict__ outv,         // [M,NCOLS] float or half
    int M)
{
    constexpr int K   = 128;
    constexpr int TR  = 16;
    constexpr int CG  = NCOLS / 4;
    constexpr int RT  = 256 / CG;
    constexpr int RPT = TR / RT;

    __shared__ float Alds[TR][K + 4];

    const int tid  = threadIdx.x;
    const int base = blockIdx.x * TR;

    for (int idx = tid; idx < TR * (K / 4); idx += 256) {
        int r  = idx / (K / 4);
        int kk = idx % (K / 4);
        float4 v = *(const float4*)(A + (size_t)(base + r) * K + kk * 4);
        *(float4*)(&Alds[r][kk * 4]) = v;
    }
    __syncthreads();

    const int cg = tid % CG;
    const int rt = tid / CG;
    const int c0 = cg * 4;
    const float* wp = W + c0;

    float4 acc[RPT];
    #pragma unroll
    for (int j = 0; j < RPT; ++j) acc[j] = make_float4(0.f, 0.f, 0.f, 0.f);

    #pragma unroll 4
    for (int k4 = 0; k4 < K; k4 += 4) {
        float4 b0 = *(const float4*)(wp + (k4 + 0) * NCOLS);
        float4 b1 = *(const float4*)(wp + (k4 + 1) * NCOLS);
        float4 b2 = *(const float4*)(wp + (k4 + 2) * NCOLS);
        float4 b3 = *(const float4*)(wp + (k4 + 3) * NCOLS);
        #pragma unroll
        for (int j = 0; j < RPT; ++j) {
            float4 a = *(const float4*)(&Alds[rt + j * RT][k4]);
            acc[j].x += a.x * b0.x + a.y * b1.x + a.z * b2.x + a.w * b3.x;
            acc[j].y += a.x * b0.y + a.y * b1.y + a.z * b2.y + a.w * b3.y;
            acc[j].z += a.x * b0.z + a.y * b1.z + a.z * b2.z + a.w * b3.z;
            acc[j].w += a.x * b0.w + a.y * b1.w + a.z * b2.w + a.w * b3.w;
        }
    }

    float4 bv = make_float4(0.f, 0.f, 0.f, 0.f);
    if (BIAS) bv = *(const float4*)(bias + c0);

    #pragma unroll
    for (int j = 0; j < RPT; ++j) {
        int r = base + rt + j * RT;
        float4 o;
        o.x = acc[j].x + bv.x;
        o.y = acc[j].y + bv.y;
        o.z = acc[j].z + bv.z;
        o.w = acc[j].w + bv.w;
        if (TANH) {
            o.x = tanhf(o.x); o.y = tanhf(o.y); o.z = tanhf(o.z); o.w = tanhf(o.w);
        }
        if (OUTHALF) {
            __half2 lo = __floats2half2_rn(o.x, o.y);
            __half2 hi = __floats2half2_rn(o.z, o.w);
            uint2 st;
            st.x = *(unsigned int*)&lo;
            st.y = *(unsigned int*)&hi;
            *(uint2*)((__half*)outv + (size_t)r * NCOLS + c0) = st;
        } else {
            *(float4*)((float*)outv + (size_t)r * NCOLS + c0) = o;
        }
    }
}

// ---------------- CSR build: block counting sort, no global atomics ----------------
__global__ __launch_bounds__(1024) void passA_hist(const int* __restrict__ dst,
                                                   int* __restrict__ counts)
{
    __shared__ int hist[NNODES];
    const int b = blockIdx.x, t = threadIdx.x;
    for (int i = t; i < NNODES; i += 1024) hist[i] = 0;
    __syncthreads();
    const int e0 = b * CHUNK, e1 = e0 + CHUNK;
    for (int e = e0 + t; e < e1; e += 1024) atomicAdd(&hist[dst[e]], 1);
    __syncthreads();
    for (int i = t; i < NNODES; i += 1024) counts[b * NNODES + i] = hist[i];
}

__global__ __launch_bounds__(256) void colsum_kernel(const int* __restrict__ counts,
                                                     int* __restrict__ total)
{
    int i = blockIdx.x * blockDim.x + threadIdx.x;
    if (i >= NNODES) return;
    int s = 0;
    for (int b = 0; b < NB; ++b) s += counts[b * NNODES + i];
    total[i] = s;
}

__global__ __launch_bounds__(1024) void scan_kernel(const int* __restrict__ total,
                                                    int* __restrict__ rs)
{
    __shared__ int part[1024];
    const int t = threadIdx.x;
    const int per = (NNODES + 1023) / 1024;
    const int begin = t * per;
    int s = 0;
    for (int j = 0; j < per; ++j) {
        int i = begin + j;
        if (i < NNODES) s += total[i];
    }
    part[t] = s;
    __syncthreads();
    for (int off = 1; off < 1024; off <<= 1) {
        int v = (t >= off) ? part[t - off] : 0;
        __syncthreads();
        part[t] += v;
        __syncthreads();
    }
    int excl = part[t] - s;
    for (int j = 0; j < per; ++j) {
        int i = begin + j;
        if (i < NNODES) {
            rs[i] = excl;
            excl += total[i];
        }
    }
    if (t == 1023) rs[NNODES] = part[1023];
}

__global__ __launch_bounds__(256) void mkbase_kernel(int* __restrict__ counts,
                                                     const int* __restrict__ rs)
{
    int i = blockIdx.x * blockDim.x + threadIdx.x;
    if (i >= NNODES) return;
    int run = rs[i];
    for (int b = 0; b < NB; ++b) {
        int c = counts[b * NNODES + i];
        counts[b * NNODES + i] = run;
        run += c;
    }
}

__global__ __launch_bounds__(1024) void passB_scatter(const int* __restrict__ src,
                                                      const int* __restrict__ dst,
                                                      const float* __restrict__ ew,
                                                      const int* __restrict__ base,
                                                      int2* __restrict__ csr)
{
    __shared__ int cur[NNODES];
    const int b = blockIdx.x, t = threadIdx.x;
    for (int i = t; i < NNODES; i += 1024) cur[i] = base[b * NNODES + i];
    __syncthreads();
    const int e0 = b * CHUNK, e1 = e0 + CHUNK;
    for (int e = e0 + t; e < e1; e += 1024) {
        int d = dst[e];
        int p = atomicAdd(&cur[d], 1);
        int2 pk;
        pk.x = src[e];
        pk.y = __float_as_int(ew[e]);
        csr[p] = pk;
    }
}

// ---------------- pull aggregation: 1 wave/node, fp16 rows, unroll x8 ----------------
__global__ __launch_bounds__(256) void aggregate_kernel(
    const __half* __restrict__ hw,     // [N,128] fp16
    const int* __restrict__ rs,        // [N+1]
    const int2* __restrict__ csr,      // [E] packed (src, w)
    const float* __restrict__ bias,    // [128]
    float* __restrict__ hout,          // [N,128] fp32
    int N)
{
    const int wid  = (blockIdx.x * blockDim.x + threadIdx.x) >> 6;
    const int lane = threadIdx.x & 63;
    if (wid >= N) return;

    const unsigned int* hwu = (const unsigned int*)hw;  // row = 64 uints (2 halves each)

    const int e0 = rs[wid];
    const int e1 = rs[wid + 1];

    float ax = 0.f, ay = 0.f;
    int e = e0;
    for (; e + 8 <= e1; e += 8) {
        int2 p[8];
        #pragma unroll
        for (int j = 0; j < 8; ++j) p[j] = csr[e + j];
        unsigned int v[8];
        #pragma unroll
        for (int j = 0; j < 8; ++j) v[j] = hwu[((size_t)p[j].x << 6) + lane];
        #pragma unroll
        for (int j = 0; j < 8; ++j) {
            float w  = __int_as_float(p[j].y);
            float2 f = __half22float2(*(const __half2*)&v[j]);
            ax += w * f.x;
            ay += w * f.y;
        }
    }
    for (; e < e1; ++e) {
        int2 p = csr[e];
        float w  = __int_as_float(p.y);
        unsigned int u = hwu[((size_t)p.x << 6) + lane];
        float2 f = __half22float2(*(const __half2*)&u);
        ax += w * f.x;
        ay += w * f.y;
    }

    float2 bv = ((const float2*)bias)[lane];
    float2 o;
    o.x = tanhf(ax + bv.x);
    o.y = tanhf(ay + bv.y);
    ((float2*)(hout + ((size_t)wid << 7)))[lane] = o;
}

// ---------------- launch ----------------
extern "C" void kernel_launch(void* const* d_in, const int* in_sizes, int n_in,
                              void* d_out, int out_size, void* d_ws, size_t ws_size,
                              hipStream_t stream)
{
    const float* x      = (const float*)d_in[0];
    const int*   ei     = (const int*)  d_in[1];   // [2,E]
    const float* ew     = (const float*)d_in[2];
    const float* enc_W  = (const float*)d_in[3];
    const float* enc_b  = (const float*)d_in[4];
    const float* conv_W = (const float*)d_in[5];   // [L,H,H]
    const float* conv_b = (const float*)d_in[6];   // [L,H]
    const float* dec_W  = (const float*)d_in[7];   // [H,C]
    const float* dec_b  = (const float*)d_in[8];   // [C]
    float* out = (float*)d_out;

    const int N = NNODES, E = NEDGES, H = HDIM;

    // workspace layout
    float*  h      = (float*)d_ws;                      // [N,H] fp32   5.12MB
    __half* hw     = (__half*)(h + (size_t)N * H);      // [N,H] fp16   2.56MB
    int2*   csr    = (int2*)((char*)hw + (size_t)N * H * sizeof(__half)); // [E] 5.12MB
    int*    counts = (int*)(csr + E);                   // [NB][N]      8MB
    int*    total  = counts + (size_t)NB * N;           // [N]
    int*    rs     = total + N;                         // [N+1]

    const int* src = ei;
    const int* dst = ei + E;

    gemm_rowtile<128, true, true, false><<<N / 16, 256, 0, stream>>>(x, enc_W, enc_b, h, N);

    passA_hist   <<<NB, 1024, 0, stream>>>(dst, counts);
    colsum_kernel<<<(N + 255) / 256, 256, 0, stream>>>(counts, total);
    scan_kernel  <<<1, 1024, 0, stream>>>(total, rs);
    mkbase_kernel<<<(N + 255) / 256, 256, 0, stream>>>(counts, rs);
    passB_scatter<<<NB, 1024, 0, stream>>>(src, dst, ew, counts, csr);

    for (int i = 0; i < NLAYER; ++i) {
        gemm_rowtile<128, false, false, true><<<N / 16, 256, 0, stream>>>(h, conv_W + (size_t)i * H * H, nullptr, hw, N);
        aggregate_kernel<<<(N + 3) / 4, 256, 0, stream>>>(hw, rs, csr, conv_b + (size_t)i * H, h, N);
    }

    gemm_rowtile<64, true, false, false><<<N / 16, 256, 0, stream>>>(h, dec_W, dec_b, out, N);
}

// Round 5
// 137.667 us; speedup vs baseline: 2.8247x; 1.6166x over previous
//
#include <hip/hip_runtime.h>
#include <hip/hip_bf16.h>
#include <hip/hip_fp16.h>

// GCN round 5: fp16 MFMA GEMMs (fp32 accum), fp16 h/hw tables (L2-resident),
// scalarized CSR edge stream in aggregate (s_load), atomic-free CSR build.

#define NNODES 10000
#define NEDGES 640000
#define HDIM   128
#define CDIM   64
#define NLAYER 3
#define NB     200
#define CHUNK  (NEDGES / NB)

typedef _Float16 half8 __attribute__((ext_vector_type(8)));
typedef float    f32x4 __attribute__((ext_vector_type(4)));

// ---------------- prep: x -> fp16 ; weights -> transposed fp16 [n][k] ----------------
__global__ __launch_bounds__(256) void prep_kernel(
    const float* __restrict__ x,
    const float* __restrict__ enc_W,
    const float* __restrict__ conv_W,
    const float* __restrict__ dec_W,
    _Float16* __restrict__ x_h,        // [N,128]
    _Float16* __restrict__ wt_all)     // enc[16384] conv[3*16384] dec[64*128]
{
    const int b = blockIdx.x, t = threadIdx.x;
    if (b < (NNODES * HDIM) / 1024) {
        int idx = (b * 256 + t) * 4;
        float4 v = *(const float4*)(x + idx);
        _Float16 o[4] = {(_Float16)v.x, (_Float16)v.y, (_Float16)v.z, (_Float16)v.w};
        *(uint2*)(x_h + idx) = *(uint2*)o;
    } else {
        int which = b - (NNODES * HDIM) / 1024;   // 0=enc 1..3=conv 4=dec
        const float* W;
        _Float16* Wt;
        int NC, total;
        if (which == 0)      { W = enc_W;                      Wt = wt_all;                 NC = 128; total = 16384; }
        else if (which <= 3) { W = conv_W + (which - 1) * 16384; Wt = wt_all + which * 16384; NC = 128; total = 16384; }
        else                 { W = dec_W;                      Wt = wt_all + 4 * 16384;     NC = 64;  total = 8192; }
        for (int idx = t; idx < total; idx += 256) {
            int n = idx >> 7, k = idx & 127;
            Wt[idx] = (_Float16)W[k * NC + n];
        }
    }
}

// ---------------- MFMA GEMM: out[M,NCOLS] = A[M,128]fp16 @ Wt^T (+bias)(+tanh) ----------------
template<int NCOLS, bool BIAS, bool TANH, bool OUTF32>
__global__ __launch_bounds__(256) void gemm_mfma(
    const _Float16* __restrict__ A,    // [M,128] fp16 row-major
    const _Float16* __restrict__ Wt,   // [NCOLS,128] fp16 (n-major)
    const float* __restrict__ bias,    // [NCOLS] fp32
    void* __restrict__ outv,           // [M,NCOLS] fp16 or fp32
    int M)
{
    constexpr int TPW = NCOLS / 64;    // n-tiles per wave (2 for 128, 1 for 64)
    const int wave = __builtin_amdgcn_readfirstlane(threadIdx.x >> 6);
    const int lane = threadIdx.x & 63;
    const int base = blockIdx.x * 16;
    const int m  = lane & 15;          // row-in-tile (A) / col-in-tile (B,D)
    const int kg = lane >> 4;          // k-group 0..3

    const _Float16* arow = A + (size_t)(base + m) * 128 + kg * 8;

    f32x4 acc[TPW];
    #pragma unroll
    for (int t = 0; t < TPW; ++t) acc[t] = (f32x4){0.f, 0.f, 0.f, 0.f};

    #pragma unroll
    for (int ks = 0; ks < 4; ++ks) {
        half8 a = *(const half8*)(arow + ks * 32);
        #pragma unroll
        for (int t = 0; t < TPW; ++t) {
            const int nt = wave + t * 4;
            half8 b = *(const half8*)(Wt + (size_t)(nt * 16 + m) * 128 + ks * 32 + kg * 8);
            acc[t] = __builtin_amdgcn_mfma_f32_16x16x32_f16(a, b, acc[t], 0, 0, 0);
        }
    }

    #pragma unroll
    for (int t = 0; t < TPW; ++t) {
        const int nt  = wave + t * 4;
        const int col = nt * 16 + m;
        float bv = BIAS ? bias[col] : 0.f;
        #pragma unroll
        for (int r = 0; r < 4; ++r) {
            int row = base + kg * 4 + r;
            float v = acc[t][r] + bv;
            if (TANH) v = tanhf(v);
            if (OUTF32) ((float*)outv)[(size_t)row * NCOLS + col] = v;
            else        ((_Float16*)outv)[(size_t)row * NCOLS + col] = (_Float16)v;
        }
    }
}

// ---------------- CSR build: block counting sort, no global atomics ----------------
__global__ __launch_bounds__(1024) void passA_hist(const int* __restrict__ dst,
                                                   int* __restrict__ counts)
{
    __shared__ int hist[NNODES];
    const int b = blockIdx.x, t = threadIdx.x;
    for (int i = t; i < NNODES; i += 1024) hist[i] = 0;
    __syncthreads();
    const int e0 = b * CHUNK, e1 = e0 + CHUNK;
    for (int e = e0 + t; e < e1; e += 1024) atomicAdd(&hist[dst[e]], 1);
    __syncthreads();
    for (int i = t; i < NNODES; i += 1024) counts[b * NNODES + i] = hist[i];
}

__global__ __launch_bounds__(256) void colsum_kernel(const int* __restrict__ counts,
                                                     int* __restrict__ total)
{
    int i = blockIdx.x * blockDim.x + threadIdx.x;
    if (i >= NNODES) return;
    int s = 0;
    for (int b = 0; b < NB; ++b) s += counts[b * NNODES + i];
    total[i] = s;
}

__global__ __launch_bounds__(1024) void scan_kernel(const int* __restrict__ total,
                                                    int* __restrict__ rs)
{
    __shared__ int part[1024];
    const int t = threadIdx.x;
    const int per = (NNODES + 1023) / 1024;
    const int begin = t * per;
    int s = 0;
    for (int j = 0; j < per; ++j) {
        int i = begin + j;
        if (i < NNODES) s += total[i];
    }
    part[t] = s;
    __syncthreads();
    for (int off = 1; off < 1024; off <<= 1) {
        int v = (t >= off) ? part[t - off] : 0;
        __syncthreads();
        part[t] += v;
        __syncthreads();
    }
    int excl = part[t] - s;
    for (int j = 0; j < per; ++j) {
        int i = begin + j;
        if (i < NNODES) {
            rs[i] = excl;
            excl += total[i];
        }
    }
    if (t == 1023) rs[NNODES] = part[1023];
}

__global__ __launch_bounds__(256) void mkbase_kernel(int* __restrict__ counts,
                                                     const int* __restrict__ rs)
{
    int i = blockIdx.x * blockDim.x + threadIdx.x;
    if (i >= NNODES) return;
    int run = rs[i];
    for (int b = 0; b < NB; ++b) {
        int c = counts[b * NNODES + i];
        counts[b * NNODES + i] = run;
        run += c;
    }
}

__global__ __launch_bounds__(1024) void passB_scatter(const int* __restrict__ src,
                                                      const int* __restrict__ dst,
                                                      const float* __restrict__ ew,
                                                      const int* __restrict__ base,
                                                      int2* __restrict__ csr)
{
    __shared__ int cur[NNODES];
    const int b = blockIdx.x, t = threadIdx.x;
    for (int i = t; i < NNODES; i += 1024) cur[i] = base[b * NNODES + i];
    __syncthreads();
    const int e0 = b * CHUNK, e1 = e0 + CHUNK;
    for (int e = e0 + t; e < e1; e += 1024) {
        int d = dst[e];
        int p = atomicAdd(&cur[d], 1);
        int2 pk;
        pk.x = src[e];
        pk.y = __float_as_int(ew[e]);
        csr[p] = pk;
    }
}

// ---------------- pull aggregation: 1 wave/node, scalar edge stream, unroll 16 ----------------
__global__ __launch_bounds__(256) void aggregate_kernel(
    const unsigned int* __restrict__ hwu,  // [N][64] fp16x2 rows
    const int* __restrict__ rs,            // [N+1]
    const int2* __restrict__ csr,          // [E] packed (src, w)
    const float* __restrict__ bias,        // [128] fp32
    unsigned int* __restrict__ hout,       // [N][64] fp16x2 rows
    int N)
{
    const int wv   = __builtin_amdgcn_readfirstlane(threadIdx.x >> 6);
    const int wid  = blockIdx.x * 4 + wv;          // wave-uniform node id (SGPR)
    const int lane = threadIdx.x & 63;
    if (wid >= N) return;

    const int e0 = rs[wid];
    const int e1 = rs[wid + 1];

    float ax = 0.f, ay = 0.f;
    int e = e0;
    for (; e + 16 <= e1; e += 16) {
        int2 p[16];
        #pragma unroll
        for (int j = 0; j < 16; ++j) p[j] = csr[e + j];          // uniform -> s_load
        unsigned int v[16];
        #pragma unroll
        for (int j = 0; j < 16; ++j) v[j] = hwu[((size_t)p[j].x << 6) + lane];
        #pragma unroll
        for (int j = 0; j < 16; ++j) {
            float w  = __int_as_float(p[j].y);
            float2 f = __half22float2(*(const __half2*)&v[j]);
            ax += w * f.x;
            ay += w * f.y;
        }
    }
    for (; e < e1; ++e) {
        int2 p = csr[e];
        float w  = __int_as_float(p.y);
        unsigned int u = hwu[((size_t)p.x << 6) + lane];
        float2 f = __half22float2(*(const __half2*)&u);
        ax += w * f.x;
        ay += w * f.y;
    }

    float2 bv = ((const float2*)bias)[lane];
    __half2 o = __floats2half2_rn(tanhf(ax + bv.x), tanhf(ay + bv.y));
    hout[((size_t)wid << 6) + lane] = *(unsigned int*)&o;
}

// ---------------- launch ----------------
extern "C" void kernel_launch(void* const* d_in, const int* in_sizes, int n_in,
                              void* d_out, int out_size, void* d_ws, size_t ws_size,
                              hipStream_t stream)
{
    const float* x      = (const float*)d_in[0];
    const int*   ei     = (const int*)  d_in[1];
    const float* ew     = (const float*)d_in[2];
    const float* enc_W  = (const float*)d_in[3];
    const float* enc_b  = (const float*)d_in[4];
    const float* conv_W = (const float*)d_in[5];
    const float* conv_b = (const float*)d_in[6];
    const float* dec_W  = (const float*)d_in[7];
    const float* dec_b  = (const float*)d_in[8];
    float* out = (float*)d_out;

    const int N = NNODES, E = NEDGES, H = HDIM;

    // workspace layout (fp16 tables)
    _Float16* x_h    = (_Float16*)d_ws;                       // [N,128]  2.56MB
    _Float16* h      = x_h + (size_t)N * H;                   // [N,128]  2.56MB
    _Float16* hw     = h + (size_t)N * H;                     // [N,128]  2.56MB
    _Float16* wt_all = hw + (size_t)N * H;                    // 73728    144KB
    int2*     csr    = (int2*)(wt_all + 5 * 16384);           // [E]      5.12MB
    int*      counts = (int*)(csr + E);                       // [NB][N]  8MB
    int*      total  = counts + (size_t)NB * N;               // [N]
    int*      rs     = total + N;                             // [N+1]

    const int* src = ei;
    const int* dst = ei + E;

    prep_kernel<<<(N * H) / 1024 + 5, 256, 0, stream>>>(x, enc_W, conv_W, dec_W, x_h, wt_all);

    // encoder (fp16 MFMA): h = tanh(x @ enc_W + enc_b)
    gemm_mfma<128, true, true, false><<<N / 16, 256, 0, stream>>>(x_h, wt_all, enc_b, h, N);

    passA_hist   <<<NB, 1024, 0, stream>>>(dst, counts);
    colsum_kernel<<<(N + 255) / 256, 256, 0, stream>>>(counts, total);
    scan_kernel  <<<1, 1024, 0, stream>>>(total, rs);
    mkbase_kernel<<<(N + 255) / 256, 256, 0, stream>>>(counts, rs);
    passB_scatter<<<NB, 1024, 0, stream>>>(src, dst, ew, counts, csr);

    for (int i = 0; i < NLAYER; ++i) {
        gemm_mfma<128, false, false, false><<<N / 16, 256, 0, stream>>>(h, wt_all + (1 + i) * 16384, nullptr, hw, N);
        aggregate_kernel<<<(N + 3) / 4, 256, 0, stream>>>((const unsigned int*)hw, rs, csr,
                                                          conv_b + (size_t)i * H, (unsigned int*)h, N);
    }

    // decoder (fp16 MFMA, fp32 out): out = h @ dec_W + dec_b
    gemm_mfma<64, true, false, true><<<N / 16, 256, 0, stream>>>(h, wt_all + 4 * 16384, dec_b, out, N);
}

// Round 6
// 135.579 us; speedup vs baseline: 2.8682x; 1.0154x over previous
//
#include <hip/hip_runtime.h>
#include <hip/hip_bf16.h>
#include <hip/hip_fp16.h>

// GCN round 6: fp16 MFMA GEMMs (fp32 accum), fp16 h/hw tables, packed 4B CSR
// (src:14b | f16 weight:16b), colsum fused into passA, x converted in-GEMM.

#define NNODES 10000
#define NEDGES 640000
#define HDIM   128
#define CDIM   64
#define NLAYER 3
#define NB     200
#define CHUNK  (NEDGES / NB)

typedef _Float16 half8 __attribute__((ext_vector_type(8)));
typedef float    f32x4 __attribute__((ext_vector_type(4)));

// ---------------- prep: weights -> transposed fp16 [n][k]; zero total ----------------
__global__ __launch_bounds__(256) void prep_kernel(
    const float* __restrict__ enc_W,
    const float* __restrict__ conv_W,
    const float* __restrict__ dec_W,
    _Float16* __restrict__ wt_all,     // enc[16384] conv[3*16384] dec[8192]
    int* __restrict__ total)
{
    const int b = blockIdx.x, t = threadIdx.x;
    if (b == 5) {
        for (int i = t; i < NNODES; i += 256) total[i] = 0;
        return;
    }
    const float* W;
    _Float16* Wt;
    int NC, totalE;
    if (b == 0)      { W = enc_W;                  Wt = wt_all;             NC = 128; totalE = 16384; }
    else if (b <= 3) { W = conv_W + (b - 1) * 16384; Wt = wt_all + b * 16384; NC = 128; totalE = 16384; }
    else             { W = dec_W;                  Wt = wt_all + 4 * 16384; NC = 64;  totalE = 8192; }
    for (int idx = t; idx < totalE; idx += 256) {
        int n = idx >> 7, k = idx & 127;
        Wt[idx] = (_Float16)W[k * NC + n];
    }
}

// ---------------- MFMA GEMM: out[M,NCOLS] = A[M,128] @ Wt^T (+bias)(+tanh) ----------------
template<int NCOLS, bool BIAS, bool TANH, bool OUTF32, bool AF32>
__global__ __launch_bounds__(256) void gemm_mfma(
    const void* __restrict__ Av,       // [M,128] fp32 or fp16 row-major
    const _Float16* __restrict__ Wt,   // [NCOLS,128] fp16 (n-major)
    const float* __restrict__ bias,    // [NCOLS] fp32
    void* __restrict__ outv,           // [M,NCOLS] fp16 or fp32
    int M)
{
    constexpr int TPW = NCOLS / 64;    // n-tiles per wave
    const int wave = __builtin_amdgcn_readfirstlane(threadIdx.x >> 6);
    const int lane = threadIdx.x & 63;
    const int base = blockIdx.x * 16;
    const int m  = lane & 15;
    const int kg = lane >> 4;
    const int row = base + m;

    f32x4 acc[TPW];
    #pragma unroll
    for (int t = 0; t < TPW; ++t) acc[t] = (f32x4){0.f, 0.f, 0.f, 0.f};

    #pragma unroll
    for (int ks = 0; ks < 4; ++ks) {
        half8 a;
        if (AF32) {
            const float* ap = (const float*)Av + (size_t)row * 128 + kg * 8 + ks * 32;
            float4 u0 = *(const float4*)(ap);
            float4 u1 = *(const float4*)(ap + 4);
            a[0] = (_Float16)u0.x; a[1] = (_Float16)u0.y;
            a[2] = (_Float16)u0.z; a[3] = (_Float16)u0.w;
            a[4] = (_Float16)u1.x; a[5] = (_Float16)u1.y;
            a[6] = (_Float16)u1.z; a[7] = (_Float16)u1.w;
        } else {
            a = *(const half8*)((const _Float16*)Av + (size_t)row * 128 + kg * 8 + ks * 32);
        }
        #pragma unroll
        for (int t = 0; t < TPW; ++t) {
            const int nt = wave + t * 4;
            half8 b = *(const half8*)(Wt + (size_t)(nt * 16 + m) * 128 + ks * 32 + kg * 8);
            acc[t] = __builtin_amdgcn_mfma_f32_16x16x32_f16(a, b, acc[t], 0, 0, 0);
        }
    }

    #pragma unroll
    for (int t = 0; t < TPW; ++t) {
        const int nt  = wave + t * 4;
        const int col = nt * 16 + m;
        float bv = BIAS ? bias[col] : 0.f;
        #pragma unroll
        for (int r = 0; r < 4; ++r) {
            int orow = base + kg * 4 + r;
            float v = acc[t][r] + bv;
            if (TANH) v = tanhf(v);
            if (OUTF32) ((float*)outv)[(size_t)orow * NCOLS + col] = v;
            else        ((_Float16*)outv)[(size_t)orow * NCOLS + col] = (_Float16)v;
        }
    }
}

// ---------------- CSR build ----------------
// passA: per-block LDS histogram -> counts[b][i]; fused colsum via atomics
__global__ __launch_bounds__(1024) void passA_hist(const int* __restrict__ dst,
                                                   int* __restrict__ counts,
                                                   int* __restrict__ total)
{
    __shared__ int hist[NNODES];
    const int b = blockIdx.x, t = threadIdx.x;
    for (int i = t; i < NNODES; i += 1024) hist[i] = 0;
    __syncthreads();
    const int e0 = b * CHUNK, e1 = e0 + CHUNK;
    for (int e = e0 + t; e < e1; e += 1024) atomicAdd(&hist[dst[e]], 1);
    __syncthreads();
    for (int i = t; i < NNODES; i += 1024) {
        int c = hist[i];
        counts[b * NNODES + i] = c;
        if (c) atomicAdd(&total[i], c);
    }
}

__global__ __launch_bounds__(1024) void scan_kernel(const int* __restrict__ total,
                                                    int* __restrict__ rs)
{
    __shared__ int part[1024];
    const int t = threadIdx.x;
    const int per = (NNODES + 1023) / 1024;
    const int begin = t * per;
    int s = 0;
    for (int j = 0; j < per; ++j) {
        int i = begin + j;
        if (i < NNODES) s += total[i];
    }
    part[t] = s;
    __syncthreads();
    for (int off = 1; off < 1024; off <<= 1) {
        int v = (t >= off) ? part[t - off] : 0;
        __syncthreads();
        part[t] += v;
        __syncthreads();
    }
    int excl = part[t] - s;
    for (int j = 0; j < per; ++j) {
        int i = begin + j;
        if (i < NNODES) {
            rs[i] = excl;
            excl += total[i];
        }
    }
    if (t == 1023) rs[NNODES] = part[1023];
}

__global__ __launch_bounds__(256) void mkbase_kernel(int* __restrict__ counts,
                                                     const int* __restrict__ rs)
{
    int i = blockIdx.x * blockDim.x + threadIdx.x;
    if (i >= NNODES) return;
    int run = rs[i];
    for (int b = 0; b < NB; ++b) {
        int c = counts[b * NNODES + i];
        counts[b * NNODES + i] = run;
        run += c;
    }
}

// passB: LDS cursor; write packed (src | f16w<<16), 4B per edge
__global__ __launch_bounds__(1024) void passB_scatter(const int* __restrict__ src,
                                                      const int* __restrict__ dst,
                                                      const float* __restrict__ ew,
                                                      const int* __restrict__ base,
                                                      unsigned int* __restrict__ csr)
{
    __shared__ int cur[NNODES];
    const int b = blockIdx.x, t = threadIdx.x;
    for (int i = t; i < NNODES; i += 1024) cur[i] = base[b * NNODES + i];
    __syncthreads();
    const int e0 = b * CHUNK, e1 = e0 + CHUNK;
    for (int e = e0 + t; e < e1; e += 1024) {
        int d = dst[e];
        int p = atomicAdd(&cur[d], 1);
        unsigned int pk = (unsigned int)src[e]
                        | ((unsigned int)__half_as_ushort(__float2half_rn(ew[e])) << 16);
        csr[p] = pk;
    }
}

// ---------------- pull aggregation: 1 wave/node, scalar packed edge stream ----------------
__global__ __launch_bounds__(256) void aggregate_kernel(
    const unsigned int* __restrict__ hwu,  // [N][64] fp16x2 rows
    const int* __restrict__ rs,            // [N+1]
    const unsigned int* __restrict__ csr,  // [E] packed (src | f16w<<16)
    const float* __restrict__ bias,        // [128] fp32
    unsigned int* __restrict__ hout,       // [N][64] fp16x2 rows
    int N)
{
    const int wv   = __builtin_amdgcn_readfirstlane(threadIdx.x >> 6);
    const int wid  = blockIdx.x * 4 + wv;          // wave-uniform node id
    const int lane = threadIdx.x & 63;
    if (wid >= N) return;

    const int e0 = rs[wid];
    const int e1 = rs[wid + 1];

    float ax = 0.f, ay = 0.f;
    int e = e0;
    for (; e + 16 <= e1; e += 16) {
        unsigned int p[16];
        #pragma unroll
        for (int j = 0; j < 16; ++j) p[j] = csr[e + j];          // uniform -> s_load
        unsigned int v[16];
        #pragma unroll
        for (int j = 0; j < 16; ++j) v[j] = hwu[((p[j] & 0x3FFFu) << 6) + lane];
        #pragma unroll
        for (int j = 0; j < 16; ++j) {
            __half wh; *(unsigned short*)&wh = (unsigned short)(p[j] >> 16);
            float w  = __half2float(wh);
            float2 f = __half22float2(*(const __half2*)&v[j]);
            ax += w * f.x;
            ay += w * f.y;
        }
    }
    for (; e + 4 <= e1; e += 4) {
        unsigned int p[4];
        #pragma unroll
        for (int j = 0; j < 4; ++j) p[j] = csr[e + j];
        unsigned int v[4];
        #pragma unroll
        for (int j = 0; j < 4; ++j) v[j] = hwu[((p[j] & 0x3FFFu) << 6) + lane];
        #pragma unroll
        for (int j = 0; j < 4; ++j) {
            __half wh; *(unsigned short*)&wh = (unsigned short)(p[j] >> 16);
            float w  = __half2float(wh);
            float2 f = __half22float2(*(const __half2*)&v[j]);
            ax += w * f.x;
            ay += w * f.y;
        }
    }
    for (; e < e1; ++e) {
        unsigned int p = csr[e];
        __half wh; *(unsigned short*)&wh = (unsigned short)(p >> 16);
        float w  = __half2float(wh);
        unsigned int u = hwu[((p & 0x3FFFu) << 6) + lane];
        float2 f = __half22float2(*(const __half2*)&u);
        ax += w * f.x;
        ay += w * f.y;
    }

    float2 bv = ((const float2*)bias)[lane];
    __half2 o = __floats2half2_rn(tanhf(ax + bv.x), tanhf(ay + bv.y));
    hout[((size_t)wid << 6) + lane] = *(unsigned int*)&o;
}

// ---------------- launch ----------------
extern "C" void kernel_launch(void* const* d_in, const int* in_sizes, int n_in,
                              void* d_out, int out_size, void* d_ws, size_t ws_size,
                              hipStream_t stream)
{
    const float* x      = (const float*)d_in[0];
    const int*   ei     = (const int*)  d_in[1];
    const float* ew     = (const float*)d_in[2];
    const float* enc_W  = (const float*)d_in[3];
    const float* enc_b  = (const float*)d_in[4];
    const float* conv_W = (const float*)d_in[5];
    const float* conv_b = (const float*)d_in[6];
    const float* dec_W  = (const float*)d_in[7];
    const float* dec_b  = (const float*)d_in[8];
    float* out = (float*)d_out;

    const int N = NNODES, E = NEDGES, H = HDIM;

    // workspace layout
    _Float16*     h      = (_Float16*)d_ws;                   // [N,128]  2.56MB
    _Float16*     hw     = h + (size_t)N * H;                 // [N,128]  2.56MB
    _Float16*     wt_all = hw + (size_t)N * H;                // 81920    160KB
    unsigned int* csr    = (unsigned int*)(wt_all + 5 * 16384); // [E]    2.56MB
    int*          counts = (int*)(csr + E);                   // [NB][N]  8MB
    int*          total  = counts + (size_t)NB * N;           // [N]
    int*          rs     = total + N;                         // [N+1]

    const int* src = ei;
    const int* dst = ei + E;

    prep_kernel<<<6, 256, 0, stream>>>(enc_W, conv_W, dec_W, wt_all, total);

    // encoder (fp32 A converted in-register): h = tanh(x @ enc_W + enc_b)
    gemm_mfma<128, true, true, false, true><<<N / 16, 256, 0, stream>>>(x, wt_all, enc_b, h, N);

    passA_hist  <<<NB, 1024, 0, stream>>>(dst, counts, total);
    scan_kernel <<<1, 1024, 0, stream>>>(total, rs);
    mkbase_kernel<<<(N + 255) / 256, 256, 0, stream>>>(counts, rs);
    passB_scatter<<<NB, 1024, 0, stream>>>(src, dst, ew, counts, csr);

    for (int i = 0; i < NLAYER; ++i) {
        gemm_mfma<128, false, false, false, false><<<N / 16, 256, 0, stream>>>(h, wt_all + (1 + i) * 16384, nullptr, hw, N);
        aggregate_kernel<<<(N + 3) / 4, 256, 0, stream>>>((const unsigned int*)hw, rs, csr,
                                                          conv_b + (size_t)i * H, (unsigned int*)h, N);
    }

    // decoder: out = h @ dec_W + dec_b (fp32 out)
    gemm_mfma<64, true, false, true, false><<<N / 16, 256, 0, stream>>>(h, wt_all + 4 * 16384, dec_b, out, N);
}